// Round 9
// baseline (764.645 us; speedup 1.0000x reference)
//
#include <hip/hip_runtime.h>
#include <stdint.h>

typedef _Float16 half8 __attribute__((ext_vector_type(8)));
typedef float f32x4 __attribute__((ext_vector_type(4)));

#define DDIM 256
#define KCODES 4096
#define BM 128
#define BN 256
#define NCH 8                  // 32-dim chunks per row
#define DELTA 0.02f
#define FLT_BIG 3.4e38f

#define GLOAD_LDS(gsrc, ldst)                                                        \
    __builtin_amdgcn_global_load_lds(                                                \
        (const __attribute__((address_space(1))) void*)(const void*)(gsrc),          \
        (__attribute__((address_space(3))) void*)(void*)(ldst), 16, 0, 0)

// ---------- fp32 -> hi/lo fp16, layout [row][ch(8)][slot(8)] half8 ----------
// slots per 32-dim chunk: 0-3 = hi quads (dims q*8..q*8+7), 4-7 = lo quads
__global__ void cvt_hl_kernel(const float* __restrict__ src, half8* __restrict__ dst) {
    int gid = blockIdx.x * 256 + threadIdx.x;   // rows*32 threads
    int q = gid & 3;
    int ch = (gid >> 2) & 7;
    long row = gid >> 5;
    const float* s = src + row * DDIM + ch * 32 + q * 8;
    const float4 f0 = ((const float4*)s)[0];
    const float4 f1 = ((const float4*)s)[1];
    float vv[8] = {f0.x, f0.y, f0.z, f0.w, f1.x, f1.y, f1.z, f1.w};
    half8 hi, lo;
    #pragma unroll
    for (int j = 0; j < 8; ++j) {
        float v = vv[j];
        _Float16 h = (_Float16)v;
        hi[j] = h; lo[j] = (_Float16)(v - (float)h);
    }
    half8* d = dst + ((row * 8 + ch) << 3);
    d[q] = hi;
    d[q + 4] = lo;
}

__global__ void enorm_kernel(const float* __restrict__ cb, float* __restrict__ en, int K) {
    int gid = blockIdx.x * blockDim.x + threadIdx.x;
    int code = gid >> 6;
    int lane = threadIdx.x & 63;
    if (code >= K) return;
    const float4 v = *reinterpret_cast<const float4*>(&cb[(size_t)code * DDIM + lane * 4]);
    float s = v.x * v.x + v.y * v.y + v.z * v.z + v.w * v.w;
    #pragma unroll
    for (int off = 32; off > 0; off >>= 1) s += __shfl_xor(s, off, 64);
    if (lane == 0) en[code] = s;
}

// ---------------- main: 4-phase interleaved MFMA GEMM + argmin + fused gather ----------------
__global__ __launch_bounds__(512, 2)
void vq_mfma_kernel(const half8* x16, const half8* __restrict__ cb16,
                    const float* __restrict__ en, const float* __restrict__ x,
                    const float* __restrict__ cb, float* out,
                    int* __restrict__ list, int* __restrict__ counter,
                    float* __restrict__ loss_accum, int N) {
    __shared__ __align__(16) half8 Abuf[2][BM * 8];   // 2 x 16 KB
    __shared__ __align__(16) half8 Bbuf[2][BN * 8];   // 2 x 32 KB
    __shared__ float en_lds[KCODES];                  // 16 KB
    __shared__ float red_d[4][BM];
    __shared__ float red_d2[4][BM];
    __shared__ int   red_i[4][BM];
    __shared__ int   binfo[BM];
    __shared__ float wsum[8];

    const int tid = threadIdx.x;
    const int lane = tid & 63;
    const int w = tid >> 6;
    const int wr = w >> 2, wc = w & 3;       // 2 x 4 waves, wave-tile 64 rows x 64 codes
    const int l15 = lane & 15, l4 = lane >> 4;
    const int brow = blockIdx.x * BM;
    const size_t ND = (size_t)N * DDIM;

    ((float4*)en_lds)[tid] = ((const float4*)en)[tid];
    ((float4*)en_lds)[tid + 512] = ((const float4*)en)[tid + 512];

    // ---- persistent stage pointers (strength-reduced) ----
    const int lrow = lane >> 3;          // row within 8-row region
    const int swz = (lane & 7) ^ lrow;   // pre-swizzled source slot
    const half8* pA0 = x16 + ((size_t)(brow + w * 8       + lrow) * NCH) * 8 + swz;
    const half8* pA1 = x16 + ((size_t)(brow + (w + 8) * 8 + lrow) * NCH) * 8 + swz;
    const half8* pB0 = cb16 + ((size_t)((w     ) * 8 + lrow) * NCH) * 8 + swz;
    const half8* pB1 = cb16 + ((size_t)((w +  8) * 8 + lrow) * NCH) * 8 + swz;
    const half8* pB2 = cb16 + ((size_t)((w + 16) * 8 + lrow) * NCH) * 8 + swz;
    const half8* pB3 = cb16 + ((size_t)((w + 24) * 8 + lrow) * NCH) * 8 + swz;

#define STAGE(b_) do {                                      \
        GLOAD_LDS(pA0, &Abuf[b_][(w     ) * 64]);           \
        GLOAD_LDS(pA1, &Abuf[b_][(w +  8) * 64]);           \
        GLOAD_LDS(pB0, &Bbuf[b_][(w     ) * 64]);           \
        GLOAD_LDS(pB1, &Bbuf[b_][(w +  8) * 64]);           \
        GLOAD_LDS(pB2, &Bbuf[b_][(w + 16) * 64]);           \
        GLOAD_LDS(pB3, &Bbuf[b_][(w + 24) * 64]);           \
    } while (0)

#define ADVANCE(roll_) do {                                 \
        const int dA = (roll_) ? -56 : 8;                   \
        const int dB = (roll_) ? 16328 : 8;                 \
        pA0 += dA; pA1 += dA;                               \
        pB0 += dB; pB1 += dB; pB2 += dB; pB3 += dB;         \
    } while (0)

    // ---- LDS frag read bases (halfword units) ----
    const int sw7 = l15 & 7;
    const _Float16* A0 = (const _Float16*)Abuf;
    const _Float16* B0 = (const _Float16*)Bbuf;
    const _Float16* aH = A0 + wr * 4096 + l15 * 64 + ((l4    ) ^ sw7) * 8;
    const _Float16* aL = A0 + wr * 4096 + l15 * 64 + ((l4 + 4) ^ sw7) * 8;
    const _Float16* bH = B0 + wc * 4096 + l15 * 64 + ((l4    ) ^ sw7) * 8;
    const _Float16* bL = B0 + wc * 4096 + l15 * 64 + ((l4 + 4) ^ sw7) * 8;

    // prologue: stage steps 0 (buf0) and 1 (buf1)
    STAGE(0); ADVANCE(false);
    STAGE(1); ADVANCE(false);
    __syncthreads();           // drains vmcnt(0): both buffers + en_lds valid

    // step-0 "prefetched" fragments a[0,1], b[0,1] from buf0
    half8 nah0 = *(const half8*)(aH);
    half8 nah1 = *(const half8*)(aH + 1024);
    half8 nal0 = *(const half8*)(aL);
    half8 nal1 = *(const half8*)(aL + 1024);
    half8 nbh0 = *(const half8*)(bH);
    half8 nbh1 = *(const half8*)(bH + 1024);
    half8 nbl0 = *(const half8*)(bL);
    half8 nbl1 = *(const half8*)(bL + 1024);

    float bestv[4], best2v[4];
    int bidv[4];
    #pragma unroll
    for (int i = 0; i < 4; ++i) { bestv[i] = FLT_BIG; best2v[i] = FLT_BIG; bidv[i] = 0; }

    const int code_sub = wc * 64 + l4 * 4;
    f32x4 acc[4][4];

#define TRI(accr, bh_, bl_, ah_, al_) do {                                              \
        accr = __builtin_amdgcn_mfma_f32_16x16x32_f16(bh_, ah_, accr, 0, 0, 0);         \
        accr = __builtin_amdgcn_mfma_f32_16x16x32_f16(bl_, ah_, accr, 0, 0, 0);         \
        accr = __builtin_amdgcn_mfma_f32_16x16x32_f16(bh_, al_, accr, 0, 0, 0);         \
    } while (0)

    for (int it = 0; it < 16; ++it) {
        #pragma unroll
        for (int m = 0; m < 4; ++m)
            #pragma unroll
            for (int n = 0; n < 4; ++n) acc[m][n] = (f32x4){0.f, 0.f, 0.f, 0.f};

        #pragma unroll
        for (int k = 0; k < 8; ++k) {
            const int ao_c = (k & 1) ? 8192 : 0;
            const int bo_c = (k & 1) ? 16384 : 0;
            const int ao_n = (k & 1) ? 0 : 8192;
            const int bo_n = (k & 1) ? 0 : 16384;

            // ---- P0: read b[2,3] (cur) ; MFMA G0 = b[0,1] x a[0,1] ----
            half8 bh2 = *(const half8*)(bH + bo_c + 2048);
            half8 bh3 = *(const half8*)(bH + bo_c + 3072);
            half8 bl2 = *(const half8*)(bL + bo_c + 2048);
            half8 bl3 = *(const half8*)(bL + bo_c + 3072);
            __builtin_amdgcn_s_setprio(1);
            TRI(acc[0][0], nbh0, nbl0, nah0, nal0);
            TRI(acc[0][1], nbh0, nbl0, nah1, nal1);
            TRI(acc[1][0], nbh1, nbl1, nah0, nal0);
            TRI(acc[1][1], nbh1, nbl1, nah1, nal1);
            __builtin_amdgcn_s_setprio(0);
            __builtin_amdgcn_s_barrier();

            // ---- P1: read a[2,3] (cur) ; MFMA G1 = b[2,3] x a[0,1] ----
            half8 ah2 = *(const half8*)(aH + ao_c + 2048);
            half8 ah3 = *(const half8*)(aH + ao_c + 3072);
            half8 al2 = *(const half8*)(aL + ao_c + 2048);
            half8 al3 = *(const half8*)(aL + ao_c + 3072);
            __builtin_amdgcn_s_setprio(1);
            TRI(acc[2][0], bh2, bl2, nah0, nal0);
            TRI(acc[2][1], bh2, bl2, nah1, nal1);
            TRI(acc[3][0], bh3, bl3, nah0, nal0);
            TRI(acc[3][1], bh3, bl3, nah1, nal1);
            __builtin_amdgcn_s_setprio(0);

            // ---- publish next buffer (stage issued 4 phases ago -> ~0 stall) ----
            asm volatile("s_waitcnt vmcnt(0)" ::: "memory");
            __builtin_amdgcn_s_barrier();
            __builtin_amdgcn_sched_barrier(0);

            // ---- P2: stage step k+2 into cur buf ; prefetch next a[0,1] ; MFMA G2 ----
            if (it < 15 || k < 6) { STAGE(k & 1); ADVANCE(k == 5); }
            if (it < 15 || k < 7) {
                nah0 = *(const half8*)(aH + ao_n);
                nah1 = *(const half8*)(aH + ao_n + 1024);
                nal0 = *(const half8*)(aL + ao_n);
                nal1 = *(const half8*)(aL + ao_n + 1024);
            }
            __builtin_amdgcn_s_setprio(1);
            TRI(acc[0][2], nbh0, nbl0, ah2, al2);
            TRI(acc[0][3], nbh0, nbl0, ah3, al3);
            TRI(acc[1][2], nbh1, nbl1, ah2, al2);
            TRI(acc[1][3], nbh1, nbl1, ah3, al3);
            __builtin_amdgcn_s_setprio(0);
            __builtin_amdgcn_s_barrier();

            // ---- P3: prefetch next b[0,1] ; MFMA G3 = b[2,3] x a[2,3] ----
            if (it < 15 || k < 7) {
                nbh0 = *(const half8*)(bH + bo_n);
                nbh1 = *(const half8*)(bH + bo_n + 1024);
                nbl0 = *(const half8*)(bL + bo_n);
                nbl1 = *(const half8*)(bL + bo_n + 1024);
            }
            __builtin_amdgcn_s_setprio(1);
            TRI(acc[2][2], bh2, bl2, ah2, al2);
            TRI(acc[2][3], bh2, bl2, ah3, al3);
            TRI(acc[3][2], bh3, bl3, ah2, al2);
            TRI(acc[3][3], bh3, bl3, ah3, al3);
            __builtin_amdgcn_s_setprio(0);
        }

        // ---- tile epilogue: dist = ||e||^2 - 2*dot ----
        const int c0 = it * BN;
        #pragma unroll
        for (int m = 0; m < 4; ++m) {
            #pragma unroll
            for (int r = 0; r < 4; ++r) {
                int code = c0 + code_sub + m * 16 + r;
                float e = en_lds[code];
                #pragma unroll
                for (int n = 0; n < 4; ++n) {
                    float dist = fmaf(-2.f, acc[m][n][r], e);
                    if (dist < bestv[n]) { best2v[n] = bestv[n]; bestv[n] = dist; bidv[n] = code; }
                    else if (dist < best2v[n]) best2v[n] = dist;
                }
            }
        }
    }
#undef STAGE
#undef ADVANCE
#undef TRI

    // ---- cross-lane merge: candidates for row (wr*64+n*16+l15) spread over l4 ----
    #pragma unroll
    for (int n = 0; n < 4; ++n) {
        float d = bestv[n], d2 = best2v[n];
        int ix = bidv[n];
        #pragma unroll
        for (int off = 16; off < 64; off <<= 1) {
            float od = __shfl_xor(d, off, 64);
            float od2 = __shfl_xor(d2, off, 64);
            int oi = __shfl_xor(ix, off, 64);
            if (od < d || (od == d && oi < ix)) { d2 = fminf(d, od2); d = od; ix = oi; }
            else d2 = fminf(d2, od);
        }
        if (l4 == 0) {
            int row = wr * 64 + n * 16 + l15;
            red_d[wc][row] = d;
            red_d2[wc][row] = d2;
            red_i[wc][row] = ix;
        }
    }
    __syncthreads();

    // ---- cross-wave merge + index write + flag append ----
    if (tid < BM) {
        float d = red_d[0][tid], d2 = red_d2[0][tid];
        int ix = red_i[0][tid];
        #pragma unroll
        for (int q = 1; q < 4; ++q) {
            float od = red_d[q][tid], od2 = red_d2[q][tid];
            int oi = red_i[q][tid];
            if (od < d || (od == d && oi < ix)) { d2 = fminf(d, od2); d = od; ix = oi; }
            else d2 = fminf(d2, od);
        }
        int fl = (d2 - d < DELTA) ? 1 : 0;
        out[ND + 1 + brow + tid] = (float)ix;
        binfo[tid] = ix | (fl << 16);
        if (fl) {
            int pos = atomicAdd(counter, 1);
            list[pos] = brow + tid;
        }
    }
    __syncthreads();

    // ---- fused gather + loss (flagged rows: provisional write, no loss) ----
    float lsum = 0.f;
    #pragma unroll 4
    for (int pp = 0; pp < 16; ++pp) {
        int i = tid + pp * 512;       // 0..8191 float4-units
        int row = i >> 6;
        int c4 = (i & 63) << 2;
        int info = binfo[row];
        int code = info & 0xffff;
        const float4 q = *reinterpret_cast<const float4*>(&cb[(size_t)code * DDIM + c4]);
        const float4 xv = *reinterpret_cast<const float4*>(&x[(size_t)(brow + row) * DDIM + c4]);
        float d0 = xv.x - q.x, d1 = xv.y - q.y, d2 = xv.z - q.z, d3 = xv.w - q.w;
        if (!(info >> 16)) lsum += d0 * d0 + d1 * d1 + d2 * d2 + d3 * d3;
        *reinterpret_cast<float4*>(&out[(size_t)(brow + row) * DDIM + c4]) = q;
    }
    #pragma unroll
    for (int off = 32; off > 0; off >>= 1) lsum += __shfl_xor(lsum, off, 64);
    if (lane == 0) wsum[w] = lsum;
    __syncthreads();
    if (tid == 0) {
        float tot = 0.f;
        #pragma unroll
        for (int q = 0; q < 8; ++q) tot += wsum[q];
        atomicAdd(loss_accum, tot * (0.25f / (float)ND));
    }
}

// ---------------- exact fp32 rescan: repairs flagged rows completely ----------------
__global__ __launch_bounds__(256)
void rescan_kernel(const float* __restrict__ x, const float* __restrict__ cb,
                   const float* __restrict__ en, const int* __restrict__ list,
                   const int* __restrict__ counter, float* out,
                   float* __restrict__ loss_accum, int N) {
    __shared__ __align__(16) float4 xrow4[64];
    __shared__ float wd[4];
    __shared__ int wi[4];
    __shared__ float wls[4];
    __shared__ int six;
    const int tid = threadIdx.x;
    const int w = tid >> 6;
    const int lane = tid & 63;
    const int cnt = *counter;
    const size_t ND = (size_t)N * DDIM;

    for (int it = blockIdx.x; it < cnt; it += gridDim.x) {
        const int row = list[it];
        __syncthreads();
        if (tid < 64) xrow4[tid] = ((const float4*)&x[(size_t)row * DDIM])[tid];
        __syncthreads();
        const float4 xv = xrow4[lane];
        float bd = FLT_BIG;
        int bi = 0;
        for (int i = 0; i < KCODES / 4; ++i) {
            int code = i * 4 + w;
            const float4 c4 = ((const float4*)&cb[(size_t)code * DDIM])[lane];
            float s = xv.x * c4.x + xv.y * c4.y + xv.z * c4.z + xv.w * c4.w;
            #pragma unroll
            for (int off = 1; off < 64; off <<= 1) s += __shfl_xor(s, off, 64);
            float dist = fmaf(-2.f, s, en[code]);
            if (dist < bd) { bd = dist; bi = code; }
        }
        if (lane == 0) { wd[w] = bd; wi[w] = bi; }
        __syncthreads();
        if (tid == 0) {
            float d = wd[0]; int ix = wi[0];
            #pragma unroll
            for (int q = 1; q < 4; ++q) {
                if (wd[q] < d || (wd[q] == d && wi[q] < ix)) { d = wd[q]; ix = wi[q]; }
            }
            six = ix;
            out[ND + 1 + row] = (float)ix;
        }
        __syncthreads();
        const int ix = six;
        float c = cb[(size_t)ix * DDIM + tid];
        float xs = ((const float*)xrow4)[tid];
        out[(size_t)row * DDIM + tid] = c;
        float dd = xs - c;
        float ss = dd * dd;
        #pragma unroll
        for (int off = 32; off > 0; off >>= 1) ss += __shfl_xor(ss, off, 64);
        if (lane == 0) wls[w] = ss;
        __syncthreads();
        if (tid == 0) {
            float tot = wls[0] + wls[1] + wls[2] + wls[3];
            atomicAdd(loss_accum, tot * (0.25f / (float)ND));
        }
    }
}

__global__ void loss_fin_kernel(const float* __restrict__ loss_accum,
                                float* __restrict__ out, size_t off) {
    if (blockIdx.x == 0 && threadIdx.x == 0) out[off] = *loss_accum;
}

extern "C" void kernel_launch(void* const* d_in, const int* in_sizes, int n_in,
                              void* d_out, int out_size, void* d_ws, size_t ws_size,
                              hipStream_t stream) {
    const float* x = (const float*)d_in[0];
    const float* cb = (const float*)d_in[1];
    const int N = in_sizes[0] / DDIM;    // 65536
    const int K = in_sizes[1] / DDIM;    // 4096
    float* out = (float*)d_out;

    // x16 (64 MB) lives in out[0 .. N*D) — each block reads only its own rows,
    // then overwrites them in its fused gather epilogue
    half8* x16 = (half8*)d_out;

    half8* cb16 = (half8*)d_ws;          // 4 MB
    char* p = (char*)d_ws + (4 << 20);
    float* en = (float*)p;                  p += (size_t)K * 4;
    int* list = (int*)p;                    p += (size_t)N * 4;
    int* counter = (int*)p;                 p += 64;
    float* loss_accum = (float*)p;

    hipMemsetAsync(counter, 0, sizeof(int), stream);
    hipMemsetAsync(loss_accum, 0, sizeof(float), stream);
    cvt_hl_kernel<<<(N * 32) / 256, 256, 0, stream>>>(x, x16);
    cvt_hl_kernel<<<(K * 32) / 256, 256, 0, stream>>>(cb, cb16);
    enorm_kernel<<<(K * 64) / 256, 256, 0, stream>>>(cb, en, K);
    vq_mfma_kernel<<<N / BM, 512, 0, stream>>>(x16, cb16, en, x, cb, out,
                                               list, counter, loss_accum, N);
    rescan_kernel<<<512, 256, 0, stream>>>(x, cb, en, list, counter, out, loss_accum, N);
    loss_fin_kernel<<<1, 64, 0, stream>>>(loss_accum, out, (size_t)N * DDIM);
}

// Round 10
// 758.443 us; speedup vs baseline: 1.0082x; 1.0082x over previous
//
#include <hip/hip_runtime.h>
#include <stdint.h>

typedef _Float16 half8 __attribute__((ext_vector_type(8)));
typedef float f32x4 __attribute__((ext_vector_type(4)));

#define DDIM 256
#define KCODES 4096
#define BM 256
#define BN 256
#define NCH 8                  // 32-dim chunks per row
#define DELTA 0.02f
#define FLT_BIG 3.4e38f

#define GLOAD_LDS(gsrc, ldst)                                                        \
    __builtin_amdgcn_global_load_lds(                                                \
        (const __attribute__((address_space(1))) void*)(const void*)(gsrc),          \
        (__attribute__((address_space(3))) void*)(void*)(ldst), 16, 0, 0)

// ---------- fp32 -> hi/lo fp16, layout [row][ch(8)][slot(8)] half8 ----------
// slots per 32-dim chunk: 0-3 = hi quads (dims q*8..q*8+7), 4-7 = lo quads
__global__ void cvt_hl_kernel(const float* __restrict__ src, half8* __restrict__ dst) {
    int gid = blockIdx.x * 256 + threadIdx.x;   // rows*32 threads
    int q = gid & 3;
    int ch = (gid >> 2) & 7;
    long row = gid >> 5;
    const float* s = src + row * DDIM + ch * 32 + q * 8;
    const float4 f0 = ((const float4*)s)[0];
    const float4 f1 = ((const float4*)s)[1];
    float vv[8] = {f0.x, f0.y, f0.z, f0.w, f1.x, f1.y, f1.z, f1.w};
    half8 hi, lo;
    #pragma unroll
    for (int j = 0; j < 8; ++j) {
        float v = vv[j];
        _Float16 h = (_Float16)v;
        hi[j] = h; lo[j] = (_Float16)(v - (float)h);
    }
    half8* d = dst + ((row * 8 + ch) << 3);
    d[q] = hi;
    d[q + 4] = lo;
}

__global__ void enorm_kernel(const float* __restrict__ cb, float* __restrict__ en, int K) {
    int gid = blockIdx.x * blockDim.x + threadIdx.x;
    int code = gid >> 6;
    int lane = threadIdx.x & 63;
    if (code >= K) return;
    const float4 v = *reinterpret_cast<const float4*>(&cb[(size_t)code * DDIM + lane * 4]);
    float s = v.x * v.x + v.y * v.y + v.z * v.z + v.w * v.w;
    #pragma unroll
    for (int off = 32; off > 0; off >>= 1) s += __shfl_xor(s, off, 64);
    if (lane == 0) en[code] = s;
}

// ---------------- main: BM=256, 8x4 frag wave-tile, stage-after-barrier ----------------
__global__ __launch_bounds__(512, 2)
void vq_mfma_kernel(const half8* x16, const half8* __restrict__ cb16,
                    const float* __restrict__ en, const float* __restrict__ x,
                    const float* __restrict__ cb, float* out,
                    int* __restrict__ list, int* __restrict__ counter,
                    float* __restrict__ loss_accum, int N) {
    __shared__ __align__(16) half8 Abuf[2][BM * 8];   // 2 x 32 KB
    __shared__ __align__(16) half8 Bbuf[2][BN * 8];   // 2 x 32 KB
    __shared__ float en_lds[KCODES];                  // 16 KB
    __shared__ float red_d[4][BM];                    // 4 KB
    __shared__ float red_d2[4][BM];                   // 4 KB
    __shared__ int   red_i[4][BM];                    // 4 KB
    __shared__ int   binfo[BM];
    __shared__ float wsum[8];

    const int tid = threadIdx.x;
    const int lane = tid & 63;
    const int w = tid >> 6;
    const int wr = w >> 2, wc = w & 3;       // 2 x 4 waves, wave-tile 128 rows x 64 codes
    const int l15 = lane & 15, l4 = lane >> 4;
    const int brow = blockIdx.x * BM;
    const size_t ND = (size_t)N * DDIM;

    ((float4*)en_lds)[tid] = ((const float4*)en)[tid];
    ((float4*)en_lds)[tid + 512] = ((const float4*)en)[tid + 512];

    // ---- persistent stage pointers: 4 A-regions + 4 B-regions per wave ----
    const int lrow = lane >> 3;          // row within 8-row region
    const int swz = (lane & 7) ^ lrow;   // pre-swizzled source slot
    const half8* pA0 = x16 + (size_t)(brow + (w     ) * 8 + lrow) * 64 + swz;
    const half8* pA1 = x16 + (size_t)(brow + (w +  8) * 8 + lrow) * 64 + swz;
    const half8* pA2 = x16 + (size_t)(brow + (w + 16) * 8 + lrow) * 64 + swz;
    const half8* pA3 = x16 + (size_t)(brow + (w + 24) * 8 + lrow) * 64 + swz;
    const half8* pB0 = cb16 + (size_t)((w     ) * 8 + lrow) * 64 + swz;
    const half8* pB1 = cb16 + (size_t)((w +  8) * 8 + lrow) * 64 + swz;
    const half8* pB2 = cb16 + (size_t)((w + 16) * 8 + lrow) * 64 + swz;
    const half8* pB3 = cb16 + (size_t)((w + 24) * 8 + lrow) * 64 + swz;

#define STAGE(b_) do {                                      \
        GLOAD_LDS(pA0, &Abuf[b_][(w     ) * 64]);           \
        GLOAD_LDS(pA1, &Abuf[b_][(w +  8) * 64]);           \
        GLOAD_LDS(pA2, &Abuf[b_][(w + 16) * 64]);           \
        GLOAD_LDS(pA3, &Abuf[b_][(w + 24) * 64]);           \
        GLOAD_LDS(pB0, &Bbuf[b_][(w     ) * 64]);           \
        GLOAD_LDS(pB1, &Bbuf[b_][(w +  8) * 64]);           \
        GLOAD_LDS(pB2, &Bbuf[b_][(w + 16) * 64]);           \
        GLOAD_LDS(pB3, &Bbuf[b_][(w + 24) * 64]);           \
    } while (0)

#define ADVANCE(roll_) do {                                 \
        const int dA = (roll_) ? -56 : 8;                   \
        const int dB = (roll_) ? 16328 : 8;                 \
        pA0 += dA; pA1 += dA; pA2 += dA; pA3 += dA;         \
        pB0 += dB; pB1 += dB; pB2 += dB; pB3 += dB;         \
    } while (0)

    // ---- LDS frag read bases (halfword units) ----
    // A rows: wr*128 + n*16 + l15 (n<8);  B codes: wc*64 + m*16 + l15 (m<4)
    const int sw7 = l15 & 7;
    const _Float16* A0 = (const _Float16*)Abuf;
    const _Float16* B0 = A0 + 32768;
    const _Float16* aH = A0 + wr * 8192 + l15 * 64 + ((l4    ) ^ sw7) * 8;
    const _Float16* aL = A0 + wr * 8192 + l15 * 64 + ((l4 + 4) ^ sw7) * 8;
    const _Float16* bH = B0 + wc * 4096 + l15 * 64 + ((l4    ) ^ sw7) * 8;
    const _Float16* bL = B0 + wc * 4096 + l15 * 64 + ((l4 + 4) ^ sw7) * 8;

    // prologue: stage step 0 into buf0
    STAGE(0); ADVANCE(false);

    float bestv[8], best2v[8];
    int bidv[8];
    #pragma unroll
    for (int i = 0; i < 8; ++i) { bestv[i] = FLT_BIG; best2v[i] = FLT_BIG; bidv[i] = 0; }

    const int code_sub = wc * 64 + l4 * 4;
    f32x4 acc[4][8];

#define TRI(accr, bh_, bl_, ah_, al_) do {                                              \
        accr = __builtin_amdgcn_mfma_f32_16x16x32_f16(bh_, ah_, accr, 0, 0, 0);         \
        accr = __builtin_amdgcn_mfma_f32_16x16x32_f16(bl_, ah_, accr, 0, 0, 0);         \
        accr = __builtin_amdgcn_mfma_f32_16x16x32_f16(bh_, al_, accr, 0, 0, 0);         \
    } while (0)

    for (int it = 0; it < 16; ++it) {
        #pragma unroll
        for (int m = 0; m < 4; ++m)
            #pragma unroll
            for (int n = 0; n < 8; ++n) acc[m][n] = (f32x4){0.f, 0.f, 0.f, 0.f};

        #pragma unroll
        for (int k = 0; k < 8; ++k) {
            // publishes buf(k&1) (staged one full step ago) + frees other buf
            __syncthreads();
            // stage the NEXT step into the other buffer (issued EARLY)
            if (k != 7) { STAGE((k + 1) & 1); ADVANCE(k == 6); }
            else if (it != 15) { STAGE(0); ADVANCE(false); }
            __builtin_amdgcn_sched_barrier(0);   // pin stage issue before reads/MFMA

            const int o = (k & 1) ? 16384 : 0;
            half8 a_h[8], a_l[8];
            #pragma unroll
            for (int n = 0; n < 8; ++n) {
                a_h[n] = *(const half8*)(aH + o + n * 1024);
                a_l[n] = *(const half8*)(aL + o + n * 1024);
            }
            #pragma unroll
            for (int m = 0; m < 4; ++m) {
                half8 bh = *(const half8*)(bH + o + m * 1024);
                half8 bl = *(const half8*)(bL + o + m * 1024);
                __builtin_amdgcn_s_setprio(1);
                #pragma unroll
                for (int n = 0; n < 8; ++n)
                    TRI(acc[m][n], bh, bl, a_h[n], a_l[n]);
                __builtin_amdgcn_s_setprio(0);
            }
        }

        // ---- tile epilogue: dist = ||e||^2 - 2*dot ----
        const int c0 = it * BN;
        #pragma unroll
        for (int m = 0; m < 4; ++m) {
            #pragma unroll
            for (int r = 0; r < 4; ++r) {
                int code = c0 + code_sub + m * 16 + r;
                float e = en_lds[code];
                #pragma unroll
                for (int n = 0; n < 8; ++n) {
                    float dist = fmaf(-2.f, acc[m][n][r], e);
                    if (dist < bestv[n]) { best2v[n] = bestv[n]; bestv[n] = dist; bidv[n] = code; }
                    else if (dist < best2v[n]) best2v[n] = dist;
                }
            }
        }
    }
#undef STAGE
#undef ADVANCE
#undef TRI

    // ---- cross-lane merge: candidates for row (wr*128+n*16+l15) spread over l4 ----
    #pragma unroll
    for (int n = 0; n < 8; ++n) {
        float d = bestv[n], d2 = best2v[n];
        int ix = bidv[n];
        #pragma unroll
        for (int off = 16; off < 64; off <<= 1) {
            float od = __shfl_xor(d, off, 64);
            float od2 = __shfl_xor(d2, off, 64);
            int oi = __shfl_xor(ix, off, 64);
            if (od < d || (od == d && oi < ix)) { d2 = fminf(d, od2); d = od; ix = oi; }
            else d2 = fminf(d2, od);
        }
        if (l4 == 0) {
            int row = wr * 128 + n * 16 + l15;
            red_d[wc][row] = d;
            red_d2[wc][row] = d2;
            red_i[wc][row] = ix;
        }
    }
    __syncthreads();

    // ---- cross-wave merge + index write + flag append ----
    if (tid < BM) {
        float d = red_d[0][tid], d2 = red_d2[0][tid];
        int ix = red_i[0][tid];
        #pragma unroll
        for (int q = 1; q < 4; ++q) {
            float od = red_d[q][tid], od2 = red_d2[q][tid];
            int oi = red_i[q][tid];
            if (od < d || (od == d && oi < ix)) { d2 = fminf(d, od2); d = od; ix = oi; }
            else d2 = fminf(d2, od);
        }
        int fl = (d2 - d < DELTA) ? 1 : 0;
        out[ND + 1 + brow + tid] = (float)ix;
        binfo[tid] = ix | (fl << 16);
        if (fl) {
            int pos = atomicAdd(counter, 1);
            list[pos] = brow + tid;
        }
    }
    __syncthreads();

    // ---- fused gather + loss (flagged rows: provisional write, no loss) ----
    float lsum = 0.f;
    #pragma unroll 4
    for (int pp = 0; pp < 32; ++pp) {
        int i = tid + pp * 512;       // 0..16383 float4-units
        int row = i >> 6;
        int c4 = (i & 63) << 2;
        int info = binfo[row];
        int code = info & 0xffff;
        const float4 q = *reinterpret_cast<const float4*>(&cb[(size_t)code * DDIM + c4]);
        const float4 xv = *reinterpret_cast<const float4*>(&x[(size_t)(brow + row) * DDIM + c4]);
        float d0 = xv.x - q.x, d1 = xv.y - q.y, d2 = xv.z - q.z, d3 = xv.w - q.w;
        if (!(info >> 16)) lsum += d0 * d0 + d1 * d1 + d2 * d2 + d3 * d3;
        *reinterpret_cast<float4*>(&out[(size_t)(brow + row) * DDIM + c4]) = q;
    }
    #pragma unroll
    for (int off = 32; off > 0; off >>= 1) lsum += __shfl_xor(lsum, off, 64);
    if (lane == 0) wsum[w] = lsum;
    __syncthreads();
    if (tid == 0) {
        float tot = 0.f;
        #pragma unroll
        for (int q = 0; q < 8; ++q) tot += wsum[q];
        atomicAdd(loss_accum, tot * (0.25f / (float)ND));
    }
}

// ---------------- exact fp32 rescan: repairs flagged rows completely ----------------
__global__ __launch_bounds__(256)
void rescan_kernel(const float* __restrict__ x, const float* __restrict__ cb,
                   const float* __restrict__ en, const int* __restrict__ list,
                   const int* __restrict__ counter, float* out,
                   float* __restrict__ loss_accum, int N) {
    __shared__ __align__(16) float4 xrow4[64];
    __shared__ float wd[4];
    __shared__ int wi[4];
    __shared__ float wls[4];
    __shared__ int six;
    const int tid = threadIdx.x;
    const int w = tid >> 6;
    const int lane = tid & 63;
    const int cnt = *counter;
    const size_t ND = (size_t)N * DDIM;

    for (int it = blockIdx.x; it < cnt; it += gridDim.x) {
        const int row = list[it];
        __syncthreads();
        if (tid < 64) xrow4[tid] = ((const float4*)&x[(size_t)row * DDIM])[tid];
        __syncthreads();
        const float4 xv = xrow4[lane];
        float bd = FLT_BIG;
        int bi = 0;
        for (int i = 0; i < KCODES / 4; ++i) {
            int code = i * 4 + w;
            const float4 c4 = ((const float4*)&cb[(size_t)code * DDIM])[lane];
            float s = xv.x * c4.x + xv.y * c4.y + xv.z * c4.z + xv.w * c4.w;
            #pragma unroll
            for (int off = 1; off < 64; off <<= 1) s += __shfl_xor(s, off, 64);
            float dist = fmaf(-2.f, s, en[code]);
            if (dist < bd) { bd = dist; bi = code; }
        }
        if (lane == 0) { wd[w] = bd; wi[w] = bi; }
        __syncthreads();
        if (tid == 0) {
            float d = wd[0]; int ix = wi[0];
            #pragma unroll
            for (int q = 1; q < 4; ++q) {
                if (wd[q] < d || (wd[q] == d && wi[q] < ix)) { d = wd[q]; ix = wi[q]; }
            }
            six = ix;
            out[ND + 1 + row] = (float)ix;
        }
        __syncthreads();
        const int ix = six;
        float c = cb[(size_t)ix * DDIM + tid];
        float xs = ((const float*)xrow4)[tid];
        out[(size_t)row * DDIM + tid] = c;
        float dd = xs - c;
        float ss = dd * dd;
        #pragma unroll
        for (int off = 32; off > 0; off >>= 1) ss += __shfl_xor(ss, off, 64);
        if (lane == 0) wls[w] = ss;
        __syncthreads();
        if (tid == 0) {
            float tot = wls[0] + wls[1] + wls[2] + wls[3];
            atomicAdd(loss_accum, tot * (0.25f / (float)ND));
        }
    }
}

__global__ void loss_fin_kernel(const float* __restrict__ loss_accum,
                                float* __restrict__ out, size_t off) {
    if (blockIdx.x == 0 && threadIdx.x == 0) out[off] = *loss_accum;
}

extern "C" void kernel_launch(void* const* d_in, const int* in_sizes, int n_in,
                              void* d_out, int out_size, void* d_ws, size_t ws_size,
                              hipStream_t stream) {
    const float* x = (const float*)d_in[0];
    const float* cb = (const float*)d_in[1];
    const int N = in_sizes[0] / DDIM;    // 65536
    const int K = in_sizes[1] / DDIM;    // 4096
    float* out = (float*)d_out;

    // x16 (64 MB) lives in out[0 .. N*D) — each block reads only its own rows,
    // then overwrites them in its fused gather epilogue
    half8* x16 = (half8*)d_out;

    half8* cb16 = (half8*)d_ws;          // 4 MB
    char* p = (char*)d_ws + (4 << 20);
    float* en = (float*)p;                  p += (size_t)K * 4;
    int* list = (int*)p;                    p += (size_t)N * 4;
    int* counter = (int*)p;                 p += 64;
    float* loss_accum = (float*)p;

    hipMemsetAsync(counter, 0, sizeof(int), stream);
    hipMemsetAsync(loss_accum, 0, sizeof(float), stream);
    cvt_hl_kernel<<<(N * 32) / 256, 256, 0, stream>>>(x, x16);
    cvt_hl_kernel<<<(K * 32) / 256, 256, 0, stream>>>(cb, cb16);
    enorm_kernel<<<(K * 64) / 256, 256, 0, stream>>>(cb, en, K);
    vq_mfma_kernel<<<N / BM, 512, 0, stream>>>(x16, cb16, en, x, cb, out,
                                               list, counter, loss_accum, N);
    rescan_kernel<<<512, 256, 0, stream>>>(x, cb, en, list, counter, out, loss_accum, N);
    loss_fin_kernel<<<1, 64, 0, stream>>>(loss_accum, out, (size_t)N * DDIM);
}